// Round 1
// baseline (2206.474 us; speedup 1.0000x reference)
//
#include <hip/hip_runtime.h>
#include <hip/hip_bf16.h>

// Problem: B=32, C=128 (in) -> 128 (out), H=W=56, 3x3 conv pad 1.
// Fused as one conv with IC2=256 (high channels 0..127, low 128..255).
#define BATCH 32
#define CH 128
#define IC2 256
#define HH 56
#define WW 56
#define HW (HH*WW)

// ws layout:
//   wq : float [128 oc][256 ic2][9]        = 294,912 f = 1,179,648 B
//   aq : bf16  [32 b][256 ic2][56][56]     = 25,690,112 * 2 B = 51,380,224 B
#define WQ_FLOATS (128*256*9)

// ---------------- Kernel 1: per-OC weight fake-quant ----------------
// 256 blocks: blk>>7 = which (0=high 8b, 1=low 4b), blk&127 = oc.
__global__ __launch_bounds__(256) void quant_w_kernel(
    const float* __restrict__ wh, const float* __restrict__ wl,
    float* __restrict__ wq) {
  int blk = blockIdx.x;
  int which = blk >> 7;
  int oc = blk & 127;
  const float* src = (which ? wl : wh) + (size_t)oc * 1152;
  float n = which ? 7.0f : 127.0f;   // signed narrow-range: 2^(b-1)-1

  __shared__ float red[256];
  float m = 0.0f;
  for (int e = threadIdx.x; e < 1152; e += 256) m = fmaxf(m, fabsf(src[e]));
  red[threadIdx.x] = m;
  __syncthreads();
  for (int s = 128; s > 0; s >>= 1) {
    if (threadIdx.x < s) red[threadIdx.x] = fmaxf(red[threadIdx.x], red[threadIdx.x + s]);
    __syncthreads();
  }
  float scale = red[0] / n;

  // dest index: [oc][which*128 + ic][9] = oc*2304 + which*1152 + e
  float* dst = wq + (size_t)oc * 2304 + (size_t)which * 1152;
  for (int e = threadIdx.x; e < 1152; e += 256) {
    float q = rintf(src[e] / scale);           // jnp.round = half-to-even = rintf
    q = fminf(fmaxf(q, -n), n);
    dst[e] = q * scale;
  }
}

// ---------------- Kernel 2: predictor mask + act fake-quant ----------------
// 4096 blocks: one per (b, c) plane.
__global__ __launch_bounds__(256) void quant_a_kernel(
    const float* __restrict__ x,
    const float* __restrict__ p_sh, const float* __restrict__ p_sl,
    __hip_bfloat16* __restrict__ aq) {
  int bc = blockIdx.x;
  int b = bc >> 7, c = bc & 127;
  const float* xp = x + (size_t)bc * HW;

  __shared__ float sx[HW];
  __shared__ float smask[49];
  for (int p = threadIdx.x; p < HW; p += 256) sx[p] = xp[p];
  __syncthreads();
  if (threadIdx.x < 49) {
    int bh = threadIdx.x / 7, bw = threadIdx.x % 7;
    float s = 0.0f;
    #pragma unroll
    for (int i = 0; i < 8; i++)
      #pragma unroll
      for (int j = 0; j < 8; j++)
        s += sx[(bh * 8 + i) * WW + bw * 8 + j];
    smask[threadIdx.x] = (s * (1.0f / 64.0f) >= 0.05f) ? 1.0f : 0.0f;
  }
  __syncthreads();

  float sh = *p_sh;   // 0.02
  float sl = *p_sl;   // 0.04
  __hip_bfloat16* ah = aq + ((size_t)b * IC2 + c) * HW;
  __hip_bfloat16* al = aq + ((size_t)b * IC2 + 128 + c) * HW;
  for (int p = threadIdx.x; p < HW; p += 256) {
    int h = p / WW, w = p - h * WW;
    bool msk = smask[(h >> 3) * 7 + (w >> 3)] != 0.0f;
    float xv = sx[p];
    float xh = msk ? xv : 1e-5f;
    float xl = msk ? 1e-5f : xv;
    float qh = fminf(fmaxf(rintf(xh / sh), 0.0f), 255.0f) * sh;
    float ql = fminf(fmaxf(rintf(xl / sl), 0.0f), 15.0f) * sl;
    ah[p] = __float2bfloat16(qh);
    al[p] = __float2bfloat16(ql);
  }
}

// ---------------- Kernel 3: direct fused conv ----------------
// grid (4 htiles, 32 oc-tiles, 32 b); block (64, 4).
// Thread: w = tx, output rows h0..h0+3 (h0 = 16*htile + 4*ty), OCT=4 ocs.
// Per ic: 18 bf16 act loads (6 rows x 3 cols, zero-padded), 36 uniform
// weight loads (scalarized), 144 FMAs.
#define OCT 4
__global__ __launch_bounds__(256) void conv_kernel(
    const float* __restrict__ wq,
    const __hip_bfloat16* __restrict__ aq,
    float* __restrict__ out) {
  int htile = blockIdx.x;       // 0..3
  int octb = blockIdx.y;        // 0..31
  int b = blockIdx.z;           // 0..31
  int tx = threadIdx.x;         // 0..63 (w; >=56 inactive for stores)
  int ty = threadIdx.y;         // 0..3
  int h0 = htile * 16 + ty * 4;
  int w = tx;

  float acc[OCT][4];
  #pragma unroll
  for (int o = 0; o < OCT; o++)
    #pragma unroll
    for (int i = 0; i < 4; i++) acc[o][i] = 0.0f;

  const __hip_bfloat16* abase = aq + (size_t)b * IC2 * HW;
  const float* wbase = wq + (size_t)octb * OCT * 2304;

  for (int ic = 0; ic < IC2; ic++) {
    const __hip_bfloat16* ap = abase + (size_t)ic * HW;
    float av[6][3];
    #pragma unroll
    for (int r = 0; r < 6; r++) {
      int hr = h0 - 1 + r;
      bool hok = (hr >= 0) && (hr < HH);
      #pragma unroll
      for (int k = 0; k < 3; k++) {
        int wc = w - 1 + k;
        bool ok = hok && (wc >= 0) && (wc < WW);
        av[r][k] = ok ? __bfloat162float(ap[hr * WW + wc]) : 0.0f;
      }
    }
    #pragma unroll
    for (int o = 0; o < OCT; o++) {
      const float* wp = wbase + o * 2304 + ic * 9;   // block/loop-uniform -> s_load
      float wv[9];
      #pragma unroll
      for (int t = 0; t < 9; t++) wv[t] = wp[t];
      #pragma unroll
      for (int i = 0; i < 4; i++)
        #pragma unroll
        for (int kh = 0; kh < 3; kh++)
          #pragma unroll
          for (int kw = 0; kw < 3; kw++)
            acc[o][i] += av[i + kh][kw] * wv[kh * 3 + kw];
    }
  }

  if (w < WW) {
    #pragma unroll
    for (int o = 0; o < OCT; o++) {
      int oc = octb * OCT + o;
      #pragma unroll
      for (int i = 0; i < 4; i++) {
        int h = h0 + i;
        if (h < HH)
          out[(((size_t)b * CH + oc) * HH + h) * WW + w] = acc[o][i];
      }
    }
  }
}

extern "C" void kernel_launch(void* const* d_in, const int* in_sizes, int n_in,
                              void* d_out, int out_size, void* d_ws, size_t ws_size,
                              hipStream_t stream) {
  const float* x = (const float*)d_in[0];
  const float* wh = (const float*)d_in[1];
  const float* wl = (const float*)d_in[2];
  const float* sh = (const float*)d_in[3];
  const float* sl = (const float*)d_in[4];
  float* out = (float*)d_out;

  float* wq = (float*)d_ws;
  __hip_bfloat16* aq = (__hip_bfloat16*)((char*)d_ws + WQ_FLOATS * sizeof(float));

  quant_w_kernel<<<dim3(256), dim3(256), 0, stream>>>(wh, wl, wq);
  quant_a_kernel<<<dim3(BATCH * CH), dim3(256), 0, stream>>>(x, sh, sl, aq);
  conv_kernel<<<dim3(4, 32, BATCH), dim3(64, 4), 0, stream>>>(wq, aq, out);
}

// Round 2
// 256.330 us; speedup vs baseline: 8.6079x; 8.6079x over previous
//
#include <hip/hip_runtime.h>
#include <hip/hip_bf16.h>
#include <stdint.h>

// Problem: B=32, C=128->128, 56x56, 3x3 pad 1, two quantized branches fused
// as one conv with IC2=256.  Implicit GEMM: M=B*H*W=100352, N=128, K=9*256.
#define BATCH 32
#define CH 128
#define IC2 256
#define HH 56
#define WW 56
#define HW 3136
#define M_TOTAL (BATCH*HW)

using short8  = __attribute__((ext_vector_type(8))) short;
using float4v = __attribute__((ext_vector_type(4))) float;

// ws layout (bytes):
//   wqb : bf16 [9][128 oc][256 ic2]   = 589,824   (B^T: ic contiguous)
//   zp  : 64 B zero page (for OOB halo lanes of global_load_lds)
//   aqn : bf16 [32][56][56][256]      = 51,380,224 (NHWC, ic2 contiguous)
//   msk : u8   [32][128][7][7]        = 200,704
#define WQB_OFF 0
#define ZP_OFF  589824
#define AQN_OFF 589888
#define MSK_OFF (589888 + 51380224)

#define GLD_LDS16(g, l)                                                        \
  __builtin_amdgcn_global_load_lds(                                            \
      (const __attribute__((address_space(1))) void*)(g),                      \
      (__attribute__((address_space(3))) void*)(l), 16, 0, 0)

// ---------------- Kernel 1: per-OC weight fake-quant -> bf16 B^T ------------
__global__ __launch_bounds__(256) void quant_w_kernel(
    const float* __restrict__ wh, const float* __restrict__ wl,
    __hip_bfloat16* __restrict__ wqb, float* __restrict__ zp) {
  int blk = blockIdx.x;
  int which = blk >> 7, oc = blk & 127;
  if (blk == 0 && threadIdx.x < 16) zp[threadIdx.x] = 0.0f;  // zero page
  const float* src = (which ? wl : wh) + (size_t)oc * 1152;
  float n = which ? 7.0f : 127.0f;  // signed narrow-range 2^(b-1)-1

  __shared__ float red[256];
  float m = 0.0f;
  for (int e = threadIdx.x; e < 1152; e += 256) m = fmaxf(m, fabsf(src[e]));
  red[threadIdx.x] = m;
  __syncthreads();
  for (int s = 128; s > 0; s >>= 1) {
    if (threadIdx.x < s) red[threadIdx.x] = fmaxf(red[threadIdx.x], red[threadIdx.x + s]);
    __syncthreads();
  }
  float scale = red[0] / n;

  // dest wqb[t][oc][which*128+ic]; e -> (t = e>>7, ic = e&127)
  for (int e = threadIdx.x; e < 1152; e += 256) {
    int t = e >> 7, ic = e & 127;
    float q = rintf(src[ic * 9 + t] / scale);  // jnp.round = RNE = rintf
    q = fminf(fmaxf(q, -n), n) * scale;
    wqb[((size_t)t * 128 + oc) * 256 + which * 128 + ic] = __float2bfloat16(q);
  }
}

// ---------------- Kernel 2a: predictor mask ---------------------------------
__global__ __launch_bounds__(256) void mask_kernel(
    const float* __restrict__ x, unsigned char* __restrict__ msk) {
  int bc = blockIdx.x;  // b*128 + c
  __shared__ float sx[HW];
  const float* xp = x + (size_t)bc * HW;
  for (int p = threadIdx.x; p < HW; p += 256) sx[p] = xp[p];
  __syncthreads();
  if (threadIdx.x < 49) {
    int bh = threadIdx.x / 7, bw = threadIdx.x % 7;
    float s = 0.0f;
    #pragma unroll
    for (int i = 0; i < 8; i++)
      #pragma unroll
      for (int j = 0; j < 8; j++)
        s += sx[(bh * 8 + i) * WW + bw * 8 + j];
    msk[(size_t)bc * 49 + threadIdx.x] = (s * (1.0f / 64.0f) >= 0.05f) ? 1 : 0;
  }
}

// ---------------- Kernel 2b: act fake-quant + NCHW->NHWC --------------------
// grid = (b*56 + h); LDS-transpose so both reads and writes are coalesced.
__global__ __launch_bounds__(256) void quant_a_kernel(
    const float* __restrict__ x, const unsigned char* __restrict__ msk,
    const float* __restrict__ p_sh, const float* __restrict__ p_sl,
    __hip_bfloat16* __restrict__ aqn) {
  int bh = blockIdx.x;
  int b = bh / HH, h = bh - b * HH;
  __shared__ float sx[128 * 57];          // [c][w], pad 57: conflict-free cols
  __shared__ unsigned char sm[128 * 8];   // [c][bw]
  for (int idx = threadIdx.x; idx < 128 * 56; idx += 256) {
    int c = idx / 56, w = idx - c * 56;
    sx[c * 57 + w] = x[((size_t)(b * 128 + c)) * HW + h * 56 + w];
  }
  for (int idx = threadIdx.x; idx < 128 * 7; idx += 256) {
    int c = idx / 7, bw = idx - c * 7;
    sm[c * 8 + bw] = msk[((size_t)(b * 128 + c)) * 49 + (h >> 3) * 7 + bw];
  }
  __syncthreads();
  float sh = p_sh[0], sl = p_sl[0];
  int c2 = threadIdx.x;            // lane layout = ic2 -> coalesced stores
  int c = c2 & 127, which = c2 >> 7;   // wave-uniform `which`
  __hip_bfloat16* dst = aqn + (size_t)bh * WW * 256 + c2;
  for (int w = 0; w < WW; ++w) {
    float xv = sx[c * 57 + w];
    bool mk = sm[c * 8 + (w >> 3)] != 0;
    float v;
    if (which == 0) {
      float xh = mk ? xv : 1e-5f;
      v = fminf(fmaxf(rintf(xh / sh), 0.0f), 255.0f) * sh;
    } else {
      float xl = mk ? 1e-5f : xv;
      v = fminf(fmaxf(rintf(xl / sl), 0.0f), 15.0f) * sl;
    }
    dst[(size_t)w * 256] = __float2bfloat16(v);
  }
}

// ---------------- Kernel 3: implicit-GEMM MFMA conv -------------------------
// Block: 128 m x 128 oc, K = 9 taps x 256 ic.  4 waves, each 64x64.
// Per K-chunk(32) per wave: 4 global_load_lds_dwordx4 + 8 ds_read_b128 + 16 MFMA.
__global__ __launch_bounds__(256) void conv_mfma_kernel(
    const __hip_bfloat16* __restrict__ wqb_,
    const __hip_bfloat16* __restrict__ aqn_,
    const float* __restrict__ zp_,
    float* __restrict__ out) {
  __shared__ __align__(16) char lds_raw[33792];  // max(A+B = 16K, Cs = 33792)
  short* As = (short*)lds_raw;                   // [128 m][32 k] bf16
  short* Bs = (short*)(lds_raw + 8192);          // [128 n][32 k] bf16
  float* Cs = (float*)lds_raw;                   // [64 oc][132 m] f32

  const short* aqn = (const short*)aqn_;
  const short* wqb = (const short*)wqb_;
  const short* zp  = (const short*)zp_;

  int tid = threadIdx.x;
  int lane = tid & 63, wv = tid >> 6;
  int wm = wv & 1, wn = wv >> 1;      // wave tile: (wm*64, wn*64)
  int q = lane & 3;                    // 16B quarter within a 64B k-segment
  int lr = lane & 15, quad = lane >> 4;

  int m0 = blockIdx.x * 128;

  // Per-thread staging precompute (2 rows per wave-instr group)
  int hj[2], wj[2];
  const short* abase[2];
  const short* bbase[2];
  short* ldsA[2];
  short* ldsB[2];
  #pragma unroll
  for (int j = 0; j < 2; ++j) {
    int ml = wv * 32 + j * 16 + (lane >> 2);
    int m = m0 + ml;
    int b = m / HW; int r = m - b * HW;
    hj[j] = r / 56; wj[j] = r - hj[j] * 56;
    abase[j] = aqn + (size_t)b * HW * 256 + q * 8;
    bbase[j] = wqb + (size_t)ml * 256 + q * 8;   // + t*32768 + ic0 at use
    ldsA[j] = As + (wv * 32 + j * 16) * 32;      // wave-uniform dest
    ldsB[j] = Bs + (wv * 32 + j * 16) * 32;
  }

  float4v acc[4][4];
  #pragma unroll
  for (int mi = 0; mi < 4; ++mi)
    #pragma unroll
    for (int ni = 0; ni < 4; ++ni)
      acc[mi][ni] = (float4v){0.f, 0.f, 0.f, 0.f};

  for (int t = 0; t < 9; ++t) {
    int dh = t / 3 - 1, dw = t % 3 - 1;
    #pragma unroll 1
    for (int icc = 0; icc < 8; ++icc) {
      int ic0 = icc * 32;
      __syncthreads();  // previous chunk's ds_reads done before overwrite
      #pragma unroll
      for (int j = 0; j < 2; ++j) {
        int h2 = hj[j] + dh, w2 = wj[j] + dw;
        bool ok = ((unsigned)h2 < (unsigned)HH) && ((unsigned)w2 < (unsigned)WW);
        const short* g = ok ? (abase[j] + (h2 * 56 + w2) * 256 + ic0)
                            : (zp + q * 8);
        GLD_LDS16(g, ldsA[j]);
        const short* gb = bbase[j] + t * 32768 + ic0;
        GLD_LDS16(gb, ldsB[j]);
      }
      __syncthreads();  // staging visible (compiler drains vmcnt)

      short8 af[4], bf[4];
      #pragma unroll
      for (int mi = 0; mi < 4; ++mi)
        af[mi] = *(const short8*)(As + (wm * 64 + mi * 16 + lr) * 32 + quad * 8);
      #pragma unroll
      for (int ni = 0; ni < 4; ++ni)
        bf[ni] = *(const short8*)(Bs + (wn * 64 + ni * 16 + lr) * 32 + quad * 8);
      #pragma unroll
      for (int mi = 0; mi < 4; ++mi)
        #pragma unroll
        for (int ni = 0; ni < 4; ++ni)
          acc[mi][ni] = __builtin_amdgcn_mfma_f32_16x16x32_bf16(
              af[mi], bf[ni], acc[mi][ni], 0, 0, 0);
    }
  }

  // Epilogue: LDS transpose (2 oc-half passes) -> coalesced NCHW stores
  #pragma unroll
  for (int p = 0; p < 2; ++p) {
    __syncthreads();
    if (wn == p) {
      #pragma unroll
      for (int mi = 0; mi < 4; ++mi)
        #pragma unroll
        for (int ni = 0; ni < 4; ++ni)
          #pragma unroll
          for (int rg = 0; rg < 4; ++rg)
            Cs[(ni * 16 + lr) * 132 + wm * 64 + mi * 16 + quad * 4 + rg] =
                acc[mi][ni][rg];
    }
    __syncthreads();
    for (int it = 0; it < 32; ++it) {
      int idx = it * 256 + tid;
      int ml = idx & 127, ocl = idx >> 7;
      int m = m0 + ml;
      int b = m / HW; int r = m - b * HW;
      out[((size_t)(b * 128 + p * 64 + ocl)) * HW + r] = Cs[ocl * 132 + ml];
    }
  }
}

extern "C" void kernel_launch(void* const* d_in, const int* in_sizes, int n_in,
                              void* d_out, int out_size, void* d_ws, size_t ws_size,
                              hipStream_t stream) {
  const float* x  = (const float*)d_in[0];
  const float* wh = (const float*)d_in[1];
  const float* wl = (const float*)d_in[2];
  const float* sh = (const float*)d_in[3];
  const float* sl = (const float*)d_in[4];
  float* out = (float*)d_out;

  char* ws = (char*)d_ws;
  __hip_bfloat16* wqb = (__hip_bfloat16*)(ws + WQB_OFF);
  float* zp           = (float*)(ws + ZP_OFF);
  __hip_bfloat16* aqn = (__hip_bfloat16*)(ws + AQN_OFF);
  unsigned char* msk  = (unsigned char*)(ws + MSK_OFF);

  quant_w_kernel<<<dim3(256), dim3(256), 0, stream>>>(wh, wl, wqb, zp);
  mask_kernel<<<dim3(BATCH * CH), dim3(256), 0, stream>>>(x, msk);
  quant_a_kernel<<<dim3(BATCH * HH), dim3(256), 0, stream>>>(x, msk, sh, sl, aqn);
  conv_mfma_kernel<<<dim3(M_TOTAL / 128), dim3(256), 0, stream>>>(
      (const __hip_bfloat16*)wqb, (const __hip_bfloat16*)aqn, zp, out);
}

// Round 3
// 217.018 us; speedup vs baseline: 10.1672x; 1.1811x over previous
//
#include <hip/hip_runtime.h>
#include <hip/hip_bf16.h>
#include <stdint.h>

// B=32, C=128->128, 56x56, 3x3 pad 1, two quantized branches fused as one
// conv with IC2=256.  Implicit GEMM: M=B*H*W=100352, N=128, K=9*256.
// R3: dh-grouped staging (w-shift via LDS halo), direct C stores.
#define BATCH 32
#define CH 128
#define IC2 256
#define HH 56
#define WW 56
#define HW 3136
#define M_TOTAL (BATCH*HW)

using short8   = __attribute__((ext_vector_type(8))) short;
using float4v  = __attribute__((ext_vector_type(4))) float;
using ushort4v = __attribute__((ext_vector_type(4))) unsigned short;

// ws layout (bytes):
//   wqb : bf16 [9][128 oc][256 ic2] = 589,824   (B^T: ic contiguous)
//   zp  : 512 B zero page (OOB staging lanes may add ic0 up to 448 B + 48)
//   aqn : bf16 [32][56][56][256]    = 51,380,224 (NHWC)
//   msk : u8   [32][128][7][7]      = 200,704
#define WQB_OFF 0
#define ZP_OFF  589824
#define AQN_OFF (589824 + 512)
#define MSK_OFF (AQN_OFF + 51380224)

#define GLD_LDS16(g, l)                                                        \
  __builtin_amdgcn_global_load_lds(                                            \
      (const __attribute__((address_space(1))) void*)(g),                      \
      (__attribute__((address_space(3))) void*)(l), 16, 0, 0)

// ---------------- Kernel 1: per-OC weight fake-quant -> bf16 B^T ------------
__global__ __launch_bounds__(256) void quant_w_kernel(
    const float* __restrict__ wh, const float* __restrict__ wl,
    __hip_bfloat16* __restrict__ wqb, float* __restrict__ zp) {
  int blk = blockIdx.x;
  int which = blk >> 7, oc = blk & 127;
  if (blk == 0 && threadIdx.x < 128) zp[threadIdx.x] = 0.0f;  // 512 B zero page
  const float* src = (which ? wl : wh) + (size_t)oc * 1152;
  float n = which ? 7.0f : 127.0f;  // signed narrow-range 2^(b-1)-1

  __shared__ float red[256];
  float m = 0.0f;
  for (int e = threadIdx.x; e < 1152; e += 256) m = fmaxf(m, fabsf(src[e]));
  red[threadIdx.x] = m;
  __syncthreads();
  for (int s = 128; s > 0; s >>= 1) {
    if (threadIdx.x < s) red[threadIdx.x] = fmaxf(red[threadIdx.x], red[threadIdx.x + s]);
    __syncthreads();
  }
  float scale = red[0] / n;

  // dest wqb[t][oc][which*128+ic]
  for (int e = threadIdx.x; e < 1152; e += 256) {
    int t = e >> 7, ic = e & 127;
    float q = rintf(src[ic * 9 + t] / scale);  // jnp.round = RNE = rintf
    q = fminf(fmaxf(q, -n), n) * scale;
    wqb[((size_t)t * 128 + oc) * 256 + which * 128 + ic] = __float2bfloat16(q);
  }
}

// ---------------- Kernel 2a: predictor mask ---------------------------------
__global__ __launch_bounds__(256) void mask_kernel(
    const float* __restrict__ x, unsigned char* __restrict__ msk) {
  int bc = blockIdx.x;  // b*128 + c
  __shared__ float sx[HW];
  const float* xp = x + (size_t)bc * HW;
  for (int p = threadIdx.x; p < HW; p += 256) sx[p] = xp[p];
  __syncthreads();
  if (threadIdx.x < 49) {
    int bh = threadIdx.x / 7, bw = threadIdx.x % 7;
    float s = 0.0f;
    #pragma unroll
    for (int i = 0; i < 8; i++)
      #pragma unroll
      for (int j = 0; j < 8; j++)
        s += sx[(bh * 8 + i) * WW + bw * 8 + j];
    msk[(size_t)bc * 49 + threadIdx.x] = (s * (1.0f / 64.0f) >= 0.05f) ? 1 : 0;
  }
}

// ---------------- Kernel 2b: act fake-quant + NCHW->NHWC --------------------
// grid = (b*56 + h).  float4 loads, 8 B bf16x4 stores.
__global__ __launch_bounds__(256) void quant_a_kernel(
    const float* __restrict__ x, const unsigned char* __restrict__ msk,
    const float* __restrict__ p_sh, const float* __restrict__ p_sl,
    __hip_bfloat16* __restrict__ aqn) {
  int bh = blockIdx.x;
  int b = bh / HH, h = bh - b * HH;
  __shared__ float sx[128 * 60];          // stride 60: float4-aligned, 2-way max
  __shared__ unsigned char sm[128 * 8];
  int t = threadIdx.x;
  #pragma unroll
  for (int i = 0; i < 7; ++i) {           // 1792 float4 = 128 c x 14
    int idx = t + i * 256;
    int c = idx / 14, w4 = idx - c * 14;
    *(float4v*)(sx + c * 60 + w4 * 4) =
        *(const float4v*)(x + ((size_t)(b * 128 + c)) * HW + h * 56 + w4 * 4);
  }
  for (int idx = t; idx < 128 * 7; idx += 256) {
    int c = idx / 7, bw = idx - c * 7;
    sm[c * 8 + bw] = msk[((size_t)(b * 128 + c)) * 49 + (h >> 3) * 7 + bw];
  }
  __syncthreads();
  float shs = p_sh[0], sls = p_sl[0];
  int cg = t & 3, pw = t >> 2;
  if (pw < WW) {
    unsigned short* dst = (unsigned short*)(aqn + (size_t)(bh * 56 + pw) * 256);
    int mcell = pw >> 3;
    #pragma unroll
    for (int j = 0; j < 16; ++j) {
      int c2b = j * 16 + cg * 4;          // 4 consecutive c2
      int cb = c2b & 127;
      bool hi = (j < 8);                  // which branch (uniform per j)
      unsigned short o[4];
      #pragma unroll
      for (int k = 0; k < 4; ++k) {
        int c = cb + k;
        float xv = sx[c * 60 + pw];
        bool mk = sm[c * 8 + mcell] != 0;
        float v;
        if (hi) {
          float xh = mk ? xv : 1e-5f;
          v = fminf(fmaxf(rintf(xh / shs), 0.0f), 255.0f) * shs;
        } else {
          float xl = mk ? 1e-5f : xv;
          v = fminf(fmaxf(rintf(xl / sls), 0.0f), 15.0f) * sls;
        }
        __hip_bfloat16 bv = __float2bfloat16(v);
        o[k] = *(unsigned short*)&bv;
      }
      *(ushort4v*)(dst + c2b) = (ushort4v){o[0], o[1], o[2], o[3]};
    }
  }
}

// ---------------- Kernel 3: implicit-GEMM MFMA conv (dh-grouped) ------------
// Block 128m x 128oc.  Outer: 3 dh groups; inner: 8 ic-chunks of 32.
// Per chunk: stage A rows m0-16..m0+143 (halo for dw shifts) + B 3-tap slab,
// then 3 dw x 16 MFMA per wave reading shifted LDS rows.  24 barrier pairs.
__global__ __launch_bounds__(256) void conv_mfma_kernel(
    const __hip_bfloat16* __restrict__ wqb_,
    const __hip_bfloat16* __restrict__ aqn_,
    const float* __restrict__ zp_,
    float* __restrict__ out) {
  __shared__ __align__(16) short As[160 * 32];   // 10 KB: 160 m-rows x 32 ic
  __shared__ __align__(16) short Bs[384 * 32];   // 24 KB: 3 taps x 128 oc x 32
  const short* aqn = (const short*)aqn_;
  const short* wqb = (const short*)wqb_;
  const short* zp  = (const short*)zp_;

  int tid = threadIdx.x;
  int lane = tid & 63, wv = tid >> 6;
  int wm = wv & 1, wn = wv >> 1;
  int q = lane & 3, lr = lane & 15, quad = lane >> 4;
  int m0 = blockIdx.x * 128;

  // A staging: 10 groups of 16 rows; wave wv -> groups {wv, wv+4, wv+8(<10)}
  int ng = (wv < 2) ? 3 : 2;
  int sgrp[3] = {wv, wv + 4, wv + 8};
  const short* abase[3];
  int avalid[3], ah[3];
  #pragma unroll
  for (int j = 0; j < 3; ++j) {
    int rr = sgrp[j] * 16 + (lane >> 2);
    int p = m0 + rr - 16;
    int pv = (p >= 0) && (p < M_TOTAL);
    int pc = pv ? p : 0;
    int b = pc / HW, rem = pc - b * HW;
    int hh = rem / 56, ww = rem - hh * 56;
    abase[j] = aqn + ((size_t)(b * HW + hh * 56 + ww)) * 256 + q * 8;
    avalid[j] = pv;
    ah[j] = hh;
  }
  // B staging: 6 row-groups per wave, rows j = wv*96 + i*16 + lane>>2
  const short* bbase[6];
  #pragma unroll
  for (int i = 0; i < 6; ++i) {
    int j = wv * 96 + i * 16 + (lane >> 2);
    bbase[i] = wqb + (size_t)j * 256 + q * 8;
  }
  // w-edge masks per m-fragment (dw=+-1 invalid at w edges)
  int lo_ok[4], hi_ok[4];
  #pragma unroll
  for (int mi = 0; mi < 4; ++mi) {
    int m = m0 + wm * 64 + mi * 16 + lr;
    int w = (m % HW) % 56;
    lo_ok[mi] = (w > 0);
    hi_ok[mi] = (w < 55);
  }

  float4v acc[4][4];
  #pragma unroll
  for (int mi = 0; mi < 4; ++mi)
    #pragma unroll
    for (int ni = 0; ni < 4; ++ni)
      acc[mi][ni] = (float4v){0.f, 0.f, 0.f, 0.f};

  for (int dh3 = 0; dh3 < 3; ++dh3) {
    int dh = dh3 - 1;
    const short* asrc[3];
    #pragma unroll
    for (int j = 0; j < 3; ++j) {
      int h2 = ah[j] + dh;
      bool ok = avalid[j] && ((unsigned)h2 < (unsigned)HH);
      asrc[j] = ok ? (abase[j] + dh * (56 * 256)) : (zp + q * 8);  // zp: +ic0 safe (512B)
    }
    const size_t boff = (size_t)dh3 * 98304;  // 3-tap slab of wqb
    #pragma unroll 1
    for (int icc = 0; icc < 8; ++icc) {
      int ic0 = icc * 32;
      __syncthreads();
      #pragma unroll
      for (int j = 0; j < 3; ++j)
        if (j < ng) GLD_LDS16(asrc[j] + ic0, As + sgrp[j] * 512);
      #pragma unroll
      for (int i = 0; i < 6; ++i)
        GLD_LDS16(bbase[i] + boff + ic0, Bs + (wv * 96 + i * 16) * 32);
      __syncthreads();

      #pragma unroll
      for (int dwi = 0; dwi < 3; ++dwi) {
        short8 af[4], bf[4];
        #pragma unroll
        for (int mi = 0; mi < 4; ++mi) {
          af[mi] = *(const short8*)(As + (wm * 64 + mi * 16 + lr + 15 + dwi) * 32 + quad * 8);
          if (dwi == 0 && !lo_ok[mi]) af[mi] = (short8)0;
          if (dwi == 2 && !hi_ok[mi]) af[mi] = (short8)0;
        }
        #pragma unroll
        for (int ni = 0; ni < 4; ++ni)
          bf[ni] = *(const short8*)(Bs + (dwi * 128 + wn * 64 + ni * 16 + lr) * 32 + quad * 8);
        #pragma unroll
        for (int mi = 0; mi < 4; ++mi)
          #pragma unroll
          for (int ni = 0; ni < 4; ++ni)
            acc[mi][ni] = __builtin_amdgcn_mfma_f32_16x16x32_bf16(
                af[mi], bf[ni], acc[mi][ni], 0, 0, 0);
      }
    }
  }

  // Epilogue: direct stores.  Lane holds 4 consecutive m (quad*4+rg) at oc=lr
  // within each 16x16 tile -> dwordx4, 16 oc-segments of 64 B per instr.
  #pragma unroll
  for (int mi = 0; mi < 4; ++mi) {
    int m = m0 + wm * 64 + mi * 16 + quad * 4;
    int b = m / HW, r = m - b * HW;
    float* obase = out + (size_t)b * (CH * HW) + r;
    #pragma unroll
    for (int ni = 0; ni < 4; ++ni) {
      int oc = wn * 64 + ni * 16 + lr;
      *(float4v*)(obase + (size_t)oc * HW) = acc[mi][ni];
    }
  }
}

extern "C" void kernel_launch(void* const* d_in, const int* in_sizes, int n_in,
                              void* d_out, int out_size, void* d_ws, size_t ws_size,
                              hipStream_t stream) {
  const float* x  = (const float*)d_in[0];
  const float* wh = (const float*)d_in[1];
  const float* wl = (const float*)d_in[2];
  const float* sh = (const float*)d_in[3];
  const float* sl = (const float*)d_in[4];
  float* out = (float*)d_out;

  char* ws = (char*)d_ws;
  __hip_bfloat16* wqb = (__hip_bfloat16*)(ws + WQB_OFF);
  float* zp           = (float*)(ws + ZP_OFF);
  __hip_bfloat16* aqn = (__hip_bfloat16*)(ws + AQN_OFF);
  unsigned char* msk  = (unsigned char*)(ws + MSK_OFF);

  quant_w_kernel<<<dim3(256), dim3(256), 0, stream>>>(wh, wl, wqb, zp);
  mask_kernel<<<dim3(BATCH * CH), dim3(256), 0, stream>>>(x, msk);
  quant_a_kernel<<<dim3(BATCH * HH), dim3(256), 0, stream>>>(x, msk, sh, sl, aqn);
  conv_mfma_kernel<<<dim3(M_TOTAL / 128), dim3(256), 0, stream>>>(
      (const __hip_bfloat16*)wqb, (const __hip_bfloat16*)aqn, zp, out);
}